// Round 3
// baseline (639.711 us; speedup 1.0000x reference)
//
#include <hip/hip_runtime.h>
#include <stdint.h>

#define T_SEQ 2048
#define HIDDEN 4096
#define NUM_HEADS 32
#define NUM_KV 8
#define HD 128
#define QSIZE (NUM_HEADS * HD)       /* 4096 */
#define KVSIZE (NUM_KV * HD)         /* 1024 */
#define QKV_N (QSIZE + 2 * KVSIZE)   /* 6144 */

typedef __attribute__((ext_vector_type(8))) __bf16 bf16x8;
typedef __attribute__((ext_vector_type(4))) float f32x4;

// ---------- helpers ----------
static __device__ __forceinline__ unsigned short f2bf(float f) {
  union { float f; unsigned int u; } v; v.f = f;
  unsigned int u = v.u;
  return (unsigned short)((u + 0x7FFFu + ((u >> 16) & 1u)) >> 16);
}

static __device__ __forceinline__ void async16(const void* g, void* l) {
  __builtin_amdgcn_global_load_lds((__attribute__((address_space(1))) void*)g,
                                   (__attribute__((address_space(3))) void*)l,
                                   16, 0, 0);
}

static __device__ __forceinline__ bf16x8 lds_frag(const unsigned short* p) {
  return *(const bf16x8*)p;
}

// ---------- fused fp32 -> bf16 cast of all three tensors ----------
#define N1 (T_SEQ * HIDDEN / 4)
#define N2 (QKV_N * HIDDEN / 4)
#define N3 (HIDDEN * QSIZE / 4)
__global__ void cvt_all(const float* __restrict__ h,
                        const float* __restrict__ wq,
                        const float* __restrict__ wo,
                        unsigned short* __restrict__ hb,
                        unsigned short* __restrict__ wqb,
                        unsigned short* __restrict__ wob) {
  int i = blockIdx.x * 256 + threadIdx.x;
  const float* src;
  unsigned short* dst;
  int j;
  if (i < N1) { src = h; dst = hb; j = i; }
  else if (i < N1 + N2) { src = wq; dst = wqb; j = i - N1; }
  else { src = wo; dst = wob; j = i - N1 - N2; }
  float4 f = ((const float4*)src)[j];
  ushort4 o;
  o.x = f2bf(f.x); o.y = f2bf(f.y); o.z = f2bf(f.z); o.w = f2bf(f.w);
  ((ushort4*)dst)[j] = o;
}

// ---------- GEMM: C[M][N] = A[M][K] * Bt[N][K]^T (+bias) ----------
__global__ __launch_bounds__(256) void gemm_bt(
    const unsigned short* __restrict__ A,
    const unsigned short* __restrict__ Bt,
    const float* __restrict__ bias,
    float* __restrict__ C, int M, int N, int K) {
  __shared__ unsigned short lds_a[128 * 32];
  __shared__ unsigned short lds_b[128 * 32];
  const int tid = threadIdx.x;
  const int wave = tid >> 6, lane = tid & 63;
  const int quad = lane >> 4, l16 = lane & 15;
  const int row0 = blockIdx.x * 128, col0 = blockIdx.y * 128;
  const int wm = (wave >> 1) * 64, wn = (wave & 1) * 64;

  f32x4 acc[4][4] = {};

  const int e0 = wave * 1024 + lane * 8;
  const int e1 = e0 + 512;
  const unsigned short* Ab0 = A + (size_t)(row0 + (e0 >> 5)) * K + (e0 & 31);
  const unsigned short* Ab1 = A + (size_t)(row0 + (e1 >> 5)) * K + (e1 & 31);
  const unsigned short* Bb0 = Bt + (size_t)(col0 + (e0 >> 5)) * K + (e0 & 31);
  const unsigned short* Bb1 = Bt + (size_t)(col0 + (e1 >> 5)) * K + (e1 & 31);
  unsigned short* la0 = lds_a + wave * 1024;
  unsigned short* la1 = la0 + 512;
  unsigned short* lb0 = lds_b + wave * 1024;
  unsigned short* lb1 = lb0 + 512;

  for (int k0 = 0; k0 < K; k0 += 32) {
    __syncthreads();
    async16(Ab0 + k0, la0);
    async16(Ab1 + k0, la1);
    async16(Bb0 + k0, lb0);
    async16(Bb1 + k0, lb1);
    __syncthreads();
    bf16x8 af[4], bfr[4];
#pragma unroll
    for (int mt = 0; mt < 4; mt++)
      af[mt] = lds_frag(lds_a + (wm + mt * 16 + l16) * 32 + quad * 8);
#pragma unroll
    for (int nt = 0; nt < 4; nt++)
      bfr[nt] = lds_frag(lds_b + (wn + nt * 16 + l16) * 32 + quad * 8);
#pragma unroll
    for (int mt = 0; mt < 4; mt++)
#pragma unroll
      for (int nt = 0; nt < 4; nt++)
        acc[mt][nt] = __builtin_amdgcn_mfma_f32_16x16x32_bf16(
            af[mt], bfr[nt], acc[mt][nt], 0, 0, 0);
  }

#pragma unroll
  for (int mt = 0; mt < 4; mt++) {
#pragma unroll
    for (int nt = 0; nt < 4; nt++) {
      const int c = col0 + wn + nt * 16 + l16;
      const float bv = bias ? bias[c] : 0.0f;
      const int rbase = row0 + wm + mt * 16 + quad * 4;
#pragma unroll
      for (int r = 0; r < 4; r++)
        C[(size_t)(rbase + r) * N + c] = acc[mt][nt][r] + bv;
    }
  }
}

// ---------- split-K GEMM: C += A * Bt^T (atomic accumulate, no bias) ----------
__global__ __launch_bounds__(256) void gemm_bt_splitk(
    const unsigned short* __restrict__ A,
    const unsigned short* __restrict__ Bt,
    float* __restrict__ C, int M, int N, int K, int kslice) {
  __shared__ unsigned short lds_a[128 * 32];
  __shared__ unsigned short lds_b[128 * 32];
  const int tid = threadIdx.x;
  const int wave = tid >> 6, lane = tid & 63;
  const int quad = lane >> 4, l16 = lane & 15;
  const int row0 = blockIdx.x * 128, col0 = blockIdx.y * 128;
  const int kofs = blockIdx.z * kslice;
  const int wm = (wave >> 1) * 64, wn = (wave & 1) * 64;

  f32x4 acc[4][4] = {};

  const int e0 = wave * 1024 + lane * 8;
  const int e1 = e0 + 512;
  const unsigned short* Ab0 = A + (size_t)(row0 + (e0 >> 5)) * K + kofs + (e0 & 31);
  const unsigned short* Ab1 = A + (size_t)(row0 + (e1 >> 5)) * K + kofs + (e1 & 31);
  const unsigned short* Bb0 = Bt + (size_t)(col0 + (e0 >> 5)) * K + kofs + (e0 & 31);
  const unsigned short* Bb1 = Bt + (size_t)(col0 + (e1 >> 5)) * K + kofs + (e1 & 31);
  unsigned short* la0 = lds_a + wave * 1024;
  unsigned short* la1 = la0 + 512;
  unsigned short* lb0 = lds_b + wave * 1024;
  unsigned short* lb1 = lb0 + 512;

  for (int k0 = 0; k0 < kslice; k0 += 32) {
    __syncthreads();
    async16(Ab0 + k0, la0);
    async16(Ab1 + k0, la1);
    async16(Bb0 + k0, lb0);
    async16(Bb1 + k0, lb1);
    __syncthreads();
    bf16x8 af[4], bfr[4];
#pragma unroll
    for (int mt = 0; mt < 4; mt++)
      af[mt] = lds_frag(lds_a + (wm + mt * 16 + l16) * 32 + quad * 8);
#pragma unroll
    for (int nt = 0; nt < 4; nt++)
      bfr[nt] = lds_frag(lds_b + (wn + nt * 16 + l16) * 32 + quad * 8);
#pragma unroll
    for (int mt = 0; mt < 4; mt++)
#pragma unroll
      for (int nt = 0; nt < 4; nt++)
        acc[mt][nt] = __builtin_amdgcn_mfma_f32_16x16x32_bf16(
            af[mt], bfr[nt], acc[mt][nt], 0, 0, 0);
  }

#pragma unroll
  for (int mt = 0; mt < 4; mt++) {
#pragma unroll
    for (int nt = 0; nt < 4; nt++) {
      const int c = col0 + wn + nt * 16 + l16;
      const int rbase = row0 + wm + mt * 16 + quad * 4;
#pragma unroll
      for (int r = 0; r < 4; r++)
        unsafeAtomicAdd(&C[(size_t)(rbase + r) * N + c], acc[mt][nt][r]);
    }
  }
}

// ---------- RMSNorm + RoPE (q + k only), emit head-major bf16 ----------
__global__ void norm_rope(const float* __restrict__ qkv,
                          const float* __restrict__ qw,
                          const float* __restrict__ kw,
                          unsigned short* __restrict__ q,
                          unsigned short* __restrict__ k) {
  const int slot = blockIdx.x;
  const int t = blockIdx.y;
  const int d = threadIdx.x;
  const float* src = (slot < 32)
      ? qkv + (size_t)t * QKV_N + slot * HD
      : qkv + (size_t)t * QKV_N + QSIZE + (slot - 32) * HD;
  float x = src[d];
  __shared__ float red[2];
  __shared__ float ylds[HD];
  float ss = x * x;
#pragma unroll
  for (int m = 32; m >= 1; m >>= 1) ss += __shfl_xor(ss, m, 64);
  if ((d & 63) == 0) red[d >> 6] = ss;
  __syncthreads();
  const float rn = rsqrtf((red[0] + red[1]) * (1.0f / 128.0f) + 1e-5f);
  const float* w = (slot < 32) ? qw : kw;
  const float y = x * rn * w[d];
  ylds[d] = y;
  __syncthreads();
  float out;
  if (d < 64) {
    const int j = d & 31;
    const float inv = exp2f(-(float)j * (13.28771237954945f / 32.0f));
    const float ang = (float)t * inv;
    float s, c;
    sincosf(ang, &s, &c);
    const float x1 = ylds[j], x2 = ylds[j + 32];
    out = (d < 32) ? (x1 * c - x2 * s) : (x2 * c + x1 * s);
  } else {
    out = y;
  }
  if (slot < 32) q[((size_t)slot * T_SEQ + t) * HD + d] = f2bf(out);
  else           k[((size_t)(slot - 32) * T_SEQ + t) * HD + d] = f2bf(out);
}

// ---------- V transpose: qkv_f32 v-slice -> Vt[kvh][d][T] bf16 ----------
__global__ __launch_bounds__(256) void transpose_v(
    const float* __restrict__ qkv, unsigned short* __restrict__ vt) {
  __shared__ unsigned short tile[64 * 136];
  const int kvh = blockIdx.x, tt = blockIdx.y;
  const int tid = threadIdx.x;
  {
    const int t_r = tid >> 2, d0 = (tid & 3) * 32;
    const float* src = qkv + (size_t)(tt * 64 + t_r) * QKV_N +
                       (QSIZE + KVSIZE) + kvh * HD + d0;
#pragma unroll
    for (int i = 0; i < 8; i++) {
      float4 f = ((const float4*)src)[i];
      unsigned short* dptr = tile + t_r * 136 + d0 + i * 4;
      dptr[0] = f2bf(f.x); dptr[1] = f2bf(f.y);
      dptr[2] = f2bf(f.z); dptr[3] = f2bf(f.w);
    }
  }
  __syncthreads();
  {
    const int d_r = tid >> 1, t0 = (tid & 1) * 32;
    unsigned short buf[32];
#pragma unroll
    for (int i = 0; i < 32; i++) buf[i] = tile[(t0 + i) * 136 + d_r];
    uint4* dst = (uint4*)(vt + ((size_t)kvh * HD + d_r) * T_SEQ + tt * 64 + t0);
#pragma unroll
    for (int i = 0; i < 4; i++) dst[i] = ((uint4*)buf)[i];
  }
}

// ---------- flash attention (causal, GQA 4:1), fixed-max softmax ----------
// |q| = |k| = sqrt(128) after RMSNorm => raw dot in [-128.6, 128.6].
// Fixed max M=129 makes softmax exact with no running max / rescale.
#define BC 64
#define KCH 528
#define VCH 544
#define PST 72
__global__ __launch_bounds__(256) void attn_fwd(
    const unsigned short* __restrict__ Q,   // [32][2048][128]
    const unsigned short* __restrict__ K,   // [8][2048][128]
    const unsigned short* __restrict__ Vt,  // [8][128][2048]
    unsigned short* __restrict__ O) {       // [2048][4096]
  __shared__ unsigned short lds_k[16 * KCH];
  __shared__ unsigned short lds_v[16 * VCH];
  __shared__ unsigned short lds_p[4 * 32 * PST];

  const int bx = blockIdx.x;
  const int qb = 15 - (bx >> 5);  // LPT: largest-work blocks first
  const int h = bx & 31;
  const int kvh = h >> 2;
  const int tid = threadIdx.x, wave = tid >> 6, lane = tid & 63;
  const int quad = lane >> 4, l16 = lane & 15;
  const int q0 = qb * 128;
  const int mrow0 = q0 + wave * 32;

  bf16x8 qf[2][4];
#pragma unroll
  for (int m = 0; m < 2; m++) {
    const unsigned short* qp =
        Q + ((size_t)h * T_SEQ + mrow0 + m * 16 + l16) * HD + quad * 8;
#pragma unroll
    for (int c2 = 0; c2 < 4; c2++) qf[m][c2] = *(const bf16x8*)(qp + c2 * 32);
  }

  f32x4 o_acc[2][8] = {};
  float lrow[2][4] = {};
  const float l2e_s = 1.4426950408889634f * 0.08838834764831845f;
  const float FMAX = 129.0f;
  const unsigned short* kb = K + (size_t)kvh * T_SEQ * HD;
  const unsigned short* vtb = Vt + (size_t)kvh * HD * T_SEQ;
  unsigned short* pbase = lds_p + wave * 32 * PST;

  const int nkt = 2 * (qb + 1);
  for (int kt = 0; kt < nkt; kt++) {
    const int kbase = kt * BC;
    __syncthreads();
#pragma unroll
    for (int cc = 0; cc < 4; cc++) {
      const int c = wave + cc * 4;
      async16(kb + (size_t)(kbase + c * 4 + (lane >> 4)) * HD + (lane & 15) * 8,
              lds_k + c * KCH + lane * 8);
      async16(vtb + (size_t)(c * 8 + (lane >> 3)) * T_SEQ + kbase + (lane & 7) * 8,
              lds_v + c * VCH + lane * 8);
    }
    __syncthreads();

    if (kbase > mrow0 + 31) continue;  // wave fully masked (uniform branch, no barriers below)

    // ---- S = Q K^T ----
    f32x4 s[2][4] = {};
#pragma unroll
    for (int c2 = 0; c2 < 4; c2++) {
#pragma unroll
      for (int nt = 0; nt < 4; nt++) {
        bf16x8 kf = lds_frag(lds_k + (nt * 4 + (l16 >> 2)) * KCH +
                             (l16 & 3) * 128 + c2 * 32 + quad * 8);
        s[0][nt] = __builtin_amdgcn_mfma_f32_16x16x32_bf16(qf[0][c2], kf, s[0][nt], 0, 0, 0);
        s[1][nt] = __builtin_amdgcn_mfma_f32_16x16x32_bf16(qf[1][c2], kf, s[1][nt], 0, 0, 0);
      }
    }

    // ---- softmax weights vs fixed max (exact; no rescale needed) ----
    const bool domask = (kbase + 63 > mrow0);
#pragma unroll
    for (int m = 0; m < 2; m++) {
#pragma unroll
      for (int r = 0; r < 4; r++) {
        const int row = mrow0 + m * 16 + quad * 4 + r;
        float ps = 0.f;
        unsigned short* pw = pbase + (m * 16 + quad * 4 + r) * PST + l16;
#pragma unroll
        for (int nt = 0; nt < 4; nt++) {
          float x = s[m][nt][r];
          if (domask && (kbase + nt * 16 + l16 > row)) x = -INFINITY;
          const float p = exp2f((x - FMAX) * l2e_s);
          ps += p;
          pw[nt * 16] = f2bf(p);
        }
        lrow[m][r] += ps;
      }
    }
    // P per-wave: in-wave lgkmcnt ordering, no barrier

    // ---- O += P V ----
#pragma unroll
    for (int ks = 0; ks < 2; ks++) {
      bf16x8 pa0 = lds_frag(pbase + l16 * PST + ks * 32 + quad * 8);
      bf16x8 pa1 = lds_frag(pbase + (16 + l16) * PST + ks * 32 + quad * 8);
#pragma unroll
      for (int dt = 0; dt < 8; dt++) {
        bf16x8 vf = lds_frag(lds_v + (dt * 2 + (l16 >> 3)) * VCH +
                             (l16 & 7) * 64 + ks * 32 + quad * 8);
        o_acc[0][dt] = __builtin_amdgcn_mfma_f32_16x16x32_bf16(pa0, vf, o_acc[0][dt], 0, 0, 0);
        o_acc[1][dt] = __builtin_amdgcn_mfma_f32_16x16x32_bf16(pa1, vf, o_acc[1][dt], 0, 0, 0);
      }
    }
  }

  // ---- epilogue: reduce l across the 16 lanes of each row, scale, store ----
#pragma unroll
  for (int m = 0; m < 2; m++) {
#pragma unroll
    for (int r = 0; r < 4; r++) {
      float l = lrow[m][r];
#pragma unroll
      for (int msk = 1; msk < 16; msk <<= 1) l += __shfl_xor(l, msk, 16);
      const float inv = 1.0f / l;
      const int row = mrow0 + m * 16 + quad * 4 + r;
#pragma unroll
      for (int dt = 0; dt < 8; dt++)
        O[(size_t)row * QSIZE + h * HD + dt * 16 + l16] =
            f2bf(o_acc[m][dt][r] * inv);
    }
  }
}

// ---------- launch ----------
extern "C" void kernel_launch(void* const* d_in, const int* in_sizes, int n_in,
                              void* d_out, int out_size, void* d_ws, size_t ws_size,
                              hipStream_t stream) {
  const float* hidden = (const float*)d_in[1];
  const float* w_qkv  = (const float*)d_in[2];
  const float* b_qkv  = (const float*)d_in[3];
  const float* q_norm = (const float*)d_in[4];
  const float* k_norm = (const float*)d_in[5];
  const float* w_o    = (const float*)d_in[6];
  float* out = (float*)d_out;

  char* ws = (char*)d_ws;
  unsigned short* hidden_bf = (unsigned short*)(ws + 0);          // 16 MB
  unsigned short* wqkv_bf   = (unsigned short*)(ws + 16777216);   // 48 MB
  unsigned short* wo_bf     = (unsigned short*)(ws + 67108864);   // 32 MB
  float*          qkv_f32   = (float*)(ws + 100663296);           // 48 MB
  unsigned short* q_bf      = (unsigned short*)(ws + 150994944);  // 16 MB
  unsigned short* k_bf      = (unsigned short*)(ws + 167772160);  // 4 MB
  unsigned short* vt_bf     = (unsigned short*)(ws + 171966464);  // 4 MB
  unsigned short* attn_bf   = (unsigned short*)(ws + 176160768);  // 16 MB

  hipMemsetAsync(out, 0, (size_t)T_SEQ * HIDDEN * sizeof(float), stream);

  cvt_all<<<(N1 + N2 + N3 + 255) / 256, 256, 0, stream>>>(
      hidden, w_qkv, w_o, hidden_bf, wqkv_bf, wo_bf);

  gemm_bt<<<dim3(T_SEQ / 128, QKV_N / 128), 256, 0, stream>>>(
      hidden_bf, wqkv_bf, b_qkv, qkv_f32, T_SEQ, QKV_N, HIDDEN);

  norm_rope<<<dim3(40, T_SEQ), 128, 0, stream>>>(
      qkv_f32, q_norm, k_norm, q_bf, k_bf);

  transpose_v<<<dim3(8, T_SEQ / 64), 256, 0, stream>>>(qkv_f32, vt_bf);

  attn_fwd<<<dim3(512), 256, 0, stream>>>(q_bf, k_bf, vt_bf, attn_bf);

  gemm_bt_splitk<<<dim3(T_SEQ / 128, HIDDEN / 128, 2), 256, 0, stream>>>(
      attn_bf, wo_bf, out, T_SEQ, HIDDEN, QSIZE, QSIZE / 2);
}

// Round 4
// 610.182 us; speedup vs baseline: 1.0484x; 1.0484x over previous
//
#include <hip/hip_runtime.h>
#include <stdint.h>

#define T_SEQ 2048
#define HIDDEN 4096
#define NUM_HEADS 32
#define NUM_KV 8
#define HD 128
#define QSIZE (NUM_HEADS * HD)       /* 4096 */
#define KVSIZE (NUM_KV * HD)         /* 1024 */
#define QKV_N (QSIZE + 2 * KVSIZE)   /* 6144 */

typedef __attribute__((ext_vector_type(8))) __bf16 bf16x8;
typedef __attribute__((ext_vector_type(4))) float f32x4;

// ---------- helpers ----------
static __device__ __forceinline__ unsigned short f2bf(float f) {
  union { float f; unsigned int u; } v; v.f = f;
  unsigned int u = v.u;
  return (unsigned short)((u + 0x7FFFu + ((u >> 16) & 1u)) >> 16);
}

static __device__ __forceinline__ void async16(const void* g, void* l) {
  __builtin_amdgcn_global_load_lds((__attribute__((address_space(1))) void*)g,
                                   (__attribute__((address_space(3))) void*)l,
                                   16, 0, 0);
}

static __device__ __forceinline__ bf16x8 lds_frag(const unsigned short* p) {
  return *(const bf16x8*)p;
}

// ---------- fused fp32 -> bf16 cast of all three tensors ----------
#define N1 (T_SEQ * HIDDEN / 4)
#define N2 (QKV_N * HIDDEN / 4)
#define N3 (HIDDEN * QSIZE / 4)
__global__ void cvt_all(const float* __restrict__ h,
                        const float* __restrict__ wq,
                        const float* __restrict__ wo,
                        unsigned short* __restrict__ hb,
                        unsigned short* __restrict__ wqb,
                        unsigned short* __restrict__ wob) {
  int i = blockIdx.x * 256 + threadIdx.x;
  const float* src;
  unsigned short* dst;
  int j;
  if (i < N1) { src = h; dst = hb; j = i; }
  else if (i < N1 + N2) { src = wq; dst = wqb; j = i - N1; }
  else { src = wo; dst = wob; j = i - N1 - N2; }
  float4 f = ((const float4*)src)[j];
  ushort4 o;
  o.x = f2bf(f.x); o.y = f2bf(f.y); o.z = f2bf(f.z); o.w = f2bf(f.w);
  ((ushort4*)dst)[j] = o;
}

// ---------- GEMM: C[M][N] = A[M][K] * Bt[N][K]^T (+bias) ----------
__global__ __launch_bounds__(256) void gemm_bt(
    const unsigned short* __restrict__ A,
    const unsigned short* __restrict__ Bt,
    const float* __restrict__ bias,
    float* __restrict__ C, int M, int N, int K) {
  __shared__ unsigned short lds_a[128 * 32];
  __shared__ unsigned short lds_b[128 * 32];
  const int tid = threadIdx.x;
  const int wave = tid >> 6, lane = tid & 63;
  const int quad = lane >> 4, l16 = lane & 15;
  const int row0 = blockIdx.x * 128, col0 = blockIdx.y * 128;
  const int wm = (wave >> 1) * 64, wn = (wave & 1) * 64;

  f32x4 acc[4][4] = {};

  const int e0 = wave * 1024 + lane * 8;
  const int e1 = e0 + 512;
  const unsigned short* Ab0 = A + (size_t)(row0 + (e0 >> 5)) * K + (e0 & 31);
  const unsigned short* Ab1 = A + (size_t)(row0 + (e1 >> 5)) * K + (e1 & 31);
  const unsigned short* Bb0 = Bt + (size_t)(col0 + (e0 >> 5)) * K + (e0 & 31);
  const unsigned short* Bb1 = Bt + (size_t)(col0 + (e1 >> 5)) * K + (e1 & 31);
  unsigned short* la0 = lds_a + wave * 1024;
  unsigned short* la1 = la0 + 512;
  unsigned short* lb0 = lds_b + wave * 1024;
  unsigned short* lb1 = lb0 + 512;

  for (int k0 = 0; k0 < K; k0 += 32) {
    __syncthreads();
    async16(Ab0 + k0, la0);
    async16(Ab1 + k0, la1);
    async16(Bb0 + k0, lb0);
    async16(Bb1 + k0, lb1);
    __syncthreads();
    bf16x8 af[4], bfr[4];
#pragma unroll
    for (int mt = 0; mt < 4; mt++)
      af[mt] = lds_frag(lds_a + (wm + mt * 16 + l16) * 32 + quad * 8);
#pragma unroll
    for (int nt = 0; nt < 4; nt++)
      bfr[nt] = lds_frag(lds_b + (wn + nt * 16 + l16) * 32 + quad * 8);
#pragma unroll
    for (int mt = 0; mt < 4; mt++)
#pragma unroll
      for (int nt = 0; nt < 4; nt++)
        acc[mt][nt] = __builtin_amdgcn_mfma_f32_16x16x32_bf16(
            af[mt], bfr[nt], acc[mt][nt], 0, 0, 0);
  }

#pragma unroll
  for (int mt = 0; mt < 4; mt++) {
#pragma unroll
    for (int nt = 0; nt < 4; nt++) {
      const int c = col0 + wn + nt * 16 + l16;
      const float bv = bias ? bias[c] : 0.0f;
      const int rbase = row0 + wm + mt * 16 + quad * 4;
#pragma unroll
      for (int r = 0; r < 4; r++)
        C[(size_t)(rbase + r) * N + c] = acc[mt][nt][r] + bv;
    }
  }
}

// ---------- split-K GEMM, no atomics: z=0 -> C0, z=1 -> C1 (plain stores) ----------
__global__ __launch_bounds__(256) void gemm_bt_splitk(
    const unsigned short* __restrict__ A,
    const unsigned short* __restrict__ Bt,
    float* __restrict__ C0, float* __restrict__ C1,
    int M, int N, int K, int kslice) {
  __shared__ unsigned short lds_a[128 * 32];
  __shared__ unsigned short lds_b[128 * 32];
  const int tid = threadIdx.x;
  const int wave = tid >> 6, lane = tid & 63;
  const int quad = lane >> 4, l16 = lane & 15;
  const int row0 = blockIdx.x * 128, col0 = blockIdx.y * 128;
  const int kofs = blockIdx.z * kslice;
  float* __restrict__ C = blockIdx.z ? C1 : C0;
  const int wm = (wave >> 1) * 64, wn = (wave & 1) * 64;

  f32x4 acc[4][4] = {};

  const int e0 = wave * 1024 + lane * 8;
  const int e1 = e0 + 512;
  const unsigned short* Ab0 = A + (size_t)(row0 + (e0 >> 5)) * K + kofs + (e0 & 31);
  const unsigned short* Ab1 = A + (size_t)(row0 + (e1 >> 5)) * K + kofs + (e1 & 31);
  const unsigned short* Bb0 = Bt + (size_t)(col0 + (e0 >> 5)) * K + kofs + (e0 & 31);
  const unsigned short* Bb1 = Bt + (size_t)(col0 + (e1 >> 5)) * K + kofs + (e1 & 31);
  unsigned short* la0 = lds_a + wave * 1024;
  unsigned short* la1 = la0 + 512;
  unsigned short* lb0 = lds_b + wave * 1024;
  unsigned short* lb1 = lb0 + 512;

  for (int k0 = 0; k0 < kslice; k0 += 32) {
    __syncthreads();
    async16(Ab0 + k0, la0);
    async16(Ab1 + k0, la1);
    async16(Bb0 + k0, lb0);
    async16(Bb1 + k0, lb1);
    __syncthreads();
    bf16x8 af[4], bfr[4];
#pragma unroll
    for (int mt = 0; mt < 4; mt++)
      af[mt] = lds_frag(lds_a + (wm + mt * 16 + l16) * 32 + quad * 8);
#pragma unroll
    for (int nt = 0; nt < 4; nt++)
      bfr[nt] = lds_frag(lds_b + (wn + nt * 16 + l16) * 32 + quad * 8);
#pragma unroll
    for (int mt = 0; mt < 4; mt++)
#pragma unroll
      for (int nt = 0; nt < 4; nt++)
        acc[mt][nt] = __builtin_amdgcn_mfma_f32_16x16x32_bf16(
            af[mt], bfr[nt], acc[mt][nt], 0, 0, 0);
  }

#pragma unroll
  for (int mt = 0; mt < 4; mt++) {
#pragma unroll
    for (int nt = 0; nt < 4; nt++) {
      const int c = col0 + wn + nt * 16 + l16;
      const int rbase = row0 + wm + mt * 16 + quad * 4;
#pragma unroll
      for (int r = 0; r < 4; r++)
        C[(size_t)(rbase + r) * N + c] = acc[mt][nt][r];
    }
  }
}

// ---------- out += partial (float4) ----------
__global__ void reduce_add(float* __restrict__ out,
                           const float* __restrict__ part, int n4) {
  int i = blockIdx.x * 256 + threadIdx.x;
  if (i >= n4) return;
  float4 a = ((const float4*)out)[i];
  float4 b = ((const float4*)part)[i];
  a.x += b.x; a.y += b.y; a.z += b.z; a.w += b.w;
  ((float4*)out)[i] = a;
}

// ---------- RMSNorm + RoPE, wave-per-head ----------
// grid 2048 (token), 256 threads = 4 waves; 10 iters cover 40 head-slots.
// Lane holds dims d=lane and d=lane+64. Rotary dims are exactly d<64.
__global__ __launch_bounds__(256) void norm_rope(
    const float* __restrict__ qkv,
    const float* __restrict__ qw,
    const float* __restrict__ kw,
    unsigned short* __restrict__ q,
    unsigned short* __restrict__ k) {
  const int t = blockIdx.x;
  const int wave = threadIdx.x >> 6, lane = threadIdx.x & 63;
#pragma unroll
  for (int it = 0; it < 10; it++) {
    const int slot = it * 4 + wave;
    const bool isq = slot < 32;
    const float* src = qkv + (size_t)t * QKV_N +
                       (isq ? slot * HD : QSIZE + (slot - 32) * HD);
    const float x0 = src[lane];
    const float x1 = src[lane + 64];
    float ss = x0 * x0 + x1 * x1;
#pragma unroll
    for (int m = 32; m >= 1; m >>= 1) ss += __shfl_xor(ss, m, 64);
    const float rn = rsqrtf(ss * (1.0f / 128.0f) + 1e-5f);
    const float* w = isq ? qw : kw;
    const float y0 = x0 * rn * w[lane];
    const float y1 = x1 * rn * w[lane + 64];
    // RoPE on d<64: pairs (j, j+32), j = lane&31; partner via shfl_xor 32
    const float p = __shfl_xor(y0, 32, 64);
    const int j = lane & 31;
    const float inv = exp2f(-(float)j * (13.28771237954945f / 32.0f));
    float s, c;
    sincosf((float)t * inv, &s, &c);
    const float r0 = (lane < 32) ? (y0 * c - p * s) : (y0 * c + p * s);
    unsigned short* dst = isq ? q + ((size_t)slot * T_SEQ + t) * HD
                              : k + ((size_t)(slot - 32) * T_SEQ + t) * HD;
    dst[lane] = f2bf(r0);
    dst[lane + 64] = f2bf(y1);
  }
}

// ---------- V transpose: qkv_f32 v-slice -> Vt[kvh][d][T] bf16 ----------
__global__ __launch_bounds__(256) void transpose_v(
    const float* __restrict__ qkv, unsigned short* __restrict__ vt) {
  __shared__ unsigned short tile[64 * 136];
  const int kvh = blockIdx.x, tt = blockIdx.y;
  const int tid = threadIdx.x;
  {
    const int t_r = tid >> 2, d0 = (tid & 3) * 32;
    const float* src = qkv + (size_t)(tt * 64 + t_r) * QKV_N +
                       (QSIZE + KVSIZE) + kvh * HD + d0;
#pragma unroll
    for (int i = 0; i < 8; i++) {
      float4 f = ((const float4*)src)[i];
      unsigned short* dptr = tile + t_r * 136 + d0 + i * 4;
      dptr[0] = f2bf(f.x); dptr[1] = f2bf(f.y);
      dptr[2] = f2bf(f.z); dptr[3] = f2bf(f.w);
    }
  }
  __syncthreads();
  {
    const int d_r = tid >> 1, t0 = (tid & 1) * 32;
    unsigned short buf[32];
#pragma unroll
    for (int i = 0; i < 32; i++) buf[i] = tile[(t0 + i) * 136 + d_r];
    uint4* dst = (uint4*)(vt + ((size_t)kvh * HD + d_r) * T_SEQ + tt * 64 + t0);
#pragma unroll
    for (int i = 0; i < 4; i++) dst[i] = ((uint4*)buf)[i];
  }
}

// ---------- flash attention (causal, GQA 4:1), fixed-max softmax ----------
#define BC 64
#define KCH 528
#define VCH 544
#define PST 72
__global__ __launch_bounds__(256) void attn_fwd(
    const unsigned short* __restrict__ Q,   // [32][2048][128]
    const unsigned short* __restrict__ K,   // [8][2048][128]
    const unsigned short* __restrict__ Vt,  // [8][128][2048]
    unsigned short* __restrict__ O) {       // [2048][4096]
  __shared__ unsigned short lds_k[16 * KCH];
  __shared__ unsigned short lds_v[16 * VCH];
  __shared__ unsigned short lds_p[4 * 32 * PST];

  const int bx = blockIdx.x;
  const int qb = 15 - (bx >> 5);  // LPT: largest-work blocks first
  const int h = bx & 31;
  const int kvh = h >> 2;
  const int tid = threadIdx.x, wave = tid >> 6, lane = tid & 63;
  const int quad = lane >> 4, l16 = lane & 15;
  const int q0 = qb * 128;
  const int mrow0 = q0 + wave * 32;

  bf16x8 qf[2][4];
#pragma unroll
  for (int m = 0; m < 2; m++) {
    const unsigned short* qp =
        Q + ((size_t)h * T_SEQ + mrow0 + m * 16 + l16) * HD + quad * 8;
#pragma unroll
    for (int c2 = 0; c2 < 4; c2++) qf[m][c2] = *(const bf16x8*)(qp + c2 * 32);
  }

  f32x4 o_acc[2][8] = {};
  float lrow[2][4] = {};
  const float l2e_s = 1.4426950408889634f * 0.08838834764831845f;
  const float FMAX = 129.0f;
  const unsigned short* kb = K + (size_t)kvh * T_SEQ * HD;
  const unsigned short* vtb = Vt + (size_t)kvh * HD * T_SEQ;
  unsigned short* pbase = lds_p + wave * 32 * PST;

  const int nkt = 2 * (qb + 1);
  for (int kt = 0; kt < nkt; kt++) {
    const int kbase = kt * BC;
    __syncthreads();
#pragma unroll
    for (int cc = 0; cc < 4; cc++) {
      const int c = wave + cc * 4;
      async16(kb + (size_t)(kbase + c * 4 + (lane >> 4)) * HD + (lane & 15) * 8,
              lds_k + c * KCH + lane * 8);
      async16(vtb + (size_t)(c * 8 + (lane >> 3)) * T_SEQ + kbase + (lane & 7) * 8,
              lds_v + c * VCH + lane * 8);
    }
    __syncthreads();

    if (kbase > mrow0 + 31) continue;  // wave fully masked (uniform per wave)

    // ---- S = Q K^T ----
    f32x4 s[2][4] = {};
#pragma unroll
    for (int c2 = 0; c2 < 4; c2++) {
#pragma unroll
      for (int nt = 0; nt < 4; nt++) {
        bf16x8 kf = lds_frag(lds_k + (nt * 4 + (l16 >> 2)) * KCH +
                             (l16 & 3) * 128 + c2 * 32 + quad * 8);
        s[0][nt] = __builtin_amdgcn_mfma_f32_16x16x32_bf16(qf[0][c2], kf, s[0][nt], 0, 0, 0);
        s[1][nt] = __builtin_amdgcn_mfma_f32_16x16x32_bf16(qf[1][c2], kf, s[1][nt], 0, 0, 0);
      }
    }

    // ---- softmax weights vs fixed max (exact; no rescale) ----
    const bool domask = (kbase + 63 > mrow0);
#pragma unroll
    for (int m = 0; m < 2; m++) {
#pragma unroll
      for (int r = 0; r < 4; r++) {
        const int row = mrow0 + m * 16 + quad * 4 + r;
        float ps = 0.f;
        unsigned short* pw = pbase + (m * 16 + quad * 4 + r) * PST + l16;
#pragma unroll
        for (int nt = 0; nt < 4; nt++) {
          float x = s[m][nt][r];
          if (domask && (kbase + nt * 16 + l16 > row)) x = -INFINITY;
          const float p = exp2f((x - FMAX) * l2e_s);
          ps += p;
          pw[nt * 16] = f2bf(p);
        }
        lrow[m][r] += ps;
      }
    }

    // ---- O += P V ----
#pragma unroll
    for (int ks = 0; ks < 2; ks++) {
      bf16x8 pa0 = lds_frag(pbase + l16 * PST + ks * 32 + quad * 8);
      bf16x8 pa1 = lds_frag(pbase + (16 + l16) * PST + ks * 32 + quad * 8);
#pragma unroll
      for (int dt = 0; dt < 8; dt++) {
        bf16x8 vf = lds_frag(lds_v + (dt * 2 + (l16 >> 3)) * VCH +
                             (l16 & 7) * 64 + ks * 32 + quad * 8);
        o_acc[0][dt] = __builtin_amdgcn_mfma_f32_16x16x32_bf16(pa0, vf, o_acc[0][dt], 0, 0, 0);
        o_acc[1][dt] = __builtin_amdgcn_mfma_f32_16x16x32_bf16(pa1, vf, o_acc[1][dt], 0, 0, 0);
      }
    }
  }

  // ---- epilogue ----
#pragma unroll
  for (int m = 0; m < 2; m++) {
#pragma unroll
    for (int r = 0; r < 4; r++) {
      float l = lrow[m][r];
#pragma unroll
      for (int msk = 1; msk < 16; msk <<= 1) l += __shfl_xor(l, msk, 16);
      const float inv = 1.0f / l;
      const int row = mrow0 + m * 16 + quad * 4 + r;
#pragma unroll
      for (int dt = 0; dt < 8; dt++)
        O[(size_t)row * QSIZE + h * HD + dt * 16 + l16] =
            f2bf(o_acc[m][dt][r] * inv);
    }
  }
}

// ---------- launch ----------
extern "C" void kernel_launch(void* const* d_in, const int* in_sizes, int n_in,
                              void* d_out, int out_size, void* d_ws, size_t ws_size,
                              hipStream_t stream) {
  const float* hidden = (const float*)d_in[1];
  const float* w_qkv  = (const float*)d_in[2];
  const float* b_qkv  = (const float*)d_in[3];
  const float* q_norm = (const float*)d_in[4];
  const float* k_norm = (const float*)d_in[5];
  const float* w_o    = (const float*)d_in[6];
  float* out = (float*)d_out;

  char* ws = (char*)d_ws;
  unsigned short* hidden_bf = (unsigned short*)(ws + 0);          // 16 MB
  unsigned short* wqkv_bf   = (unsigned short*)(ws + 16777216);   // 48 MB
  unsigned short* wo_bf     = (unsigned short*)(ws + 67108864);   // 32 MB
  float*          qkv_f32   = (float*)(ws + 100663296);           // 48 MB
  unsigned short* q_bf      = (unsigned short*)(ws + 150994944);  // 16 MB
  unsigned short* k_bf      = (unsigned short*)(ws + 167772160);  // 4 MB
  unsigned short* vt_bf     = (unsigned short*)(ws + 171966464);  // 4 MB
  unsigned short* attn_bf   = (unsigned short*)(ws + 176160768);  // 16 MB
  // split-K partial aliases qkv_f32 (dead after norm_rope + transpose_v)
  float*          part_f32  = (float*)(ws + 100663296);           // 32 MB

  cvt_all<<<(N1 + N2 + N3 + 255) / 256, 256, 0, stream>>>(
      hidden, w_qkv, w_o, hidden_bf, wqkv_bf, wo_bf);

  gemm_bt<<<dim3(T_SEQ / 128, QKV_N / 128), 256, 0, stream>>>(
      hidden_bf, wqkv_bf, b_qkv, qkv_f32, T_SEQ, QKV_N, HIDDEN);

  norm_rope<<<dim3(T_SEQ), 256, 0, stream>>>(
      qkv_f32, q_norm, k_norm, q_bf, k_bf);

  transpose_v<<<dim3(8, T_SEQ / 64), 256, 0, stream>>>(qkv_f32, vt_bf);

  attn_fwd<<<dim3(512), 256, 0, stream>>>(q_bf, k_bf, vt_bf, attn_bf);

  gemm_bt_splitk<<<dim3(T_SEQ / 128, HIDDEN / 128, 2), 256, 0, stream>>>(
      attn_bf, wo_bf, out, part_f32, T_SEQ, HIDDEN, QSIZE, QSIZE / 2);

  reduce_add<<<(T_SEQ * HIDDEN / 4 + 255) / 256, 256, 0, stream>>>(
      out, part_f32, T_SEQ * HIDDEN / 4);
}

// Round 6
// 581.148 us; speedup vs baseline: 1.1008x; 1.0500x over previous
//
#include <hip/hip_runtime.h>
#include <stdint.h>

#define T_SEQ 2048
#define HIDDEN 4096
#define NUM_HEADS 32
#define NUM_KV 8
#define HD 128
#define QSIZE (NUM_HEADS * HD)       /* 4096 */
#define KVSIZE (NUM_KV * HD)         /* 1024 */
#define QKV_N (QSIZE + 2 * KVSIZE)   /* 6144 */

typedef __attribute__((ext_vector_type(8))) __bf16 bf16x8;
typedef __attribute__((ext_vector_type(4))) float f32x4;

// ---------- helpers ----------
static __device__ __forceinline__ unsigned short f2bf(float f) {
  union { float f; unsigned int u; } v; v.f = f;
  unsigned int u = v.u;
  return (unsigned short)((u + 0x7FFFu + ((u >> 16) & 1u)) >> 16);
}

static __device__ __forceinline__ void async16(const void* g, void* l) {
  __builtin_amdgcn_global_load_lds((__attribute__((address_space(1))) void*)g,
                                   (__attribute__((address_space(3))) void*)l,
                                   16, 0, 0);
}

static __device__ __forceinline__ bf16x8 lds_frag(const unsigned short* p) {
  return *(const bf16x8*)p;
}

// ---------- fused fp32 -> bf16 cast of all three tensors ----------
#define N1 (T_SEQ * HIDDEN / 4)
#define N2 (QKV_N * HIDDEN / 4)
#define N3 (HIDDEN * QSIZE / 4)
__global__ void cvt_all(const float* __restrict__ h,
                        const float* __restrict__ wq,
                        const float* __restrict__ wo,
                        unsigned short* __restrict__ hb,
                        unsigned short* __restrict__ wqb,
                        unsigned short* __restrict__ wob) {
  int i = blockIdx.x * 256 + threadIdx.x;
  const float* src;
  unsigned short* dst;
  int j;
  if (i < N1) { src = h; dst = hb; j = i; }
  else if (i < N1 + N2) { src = wq; dst = wqb; j = i - N1; }
  else { src = wo; dst = wob; j = i - N1 - N2; }
  float4 f = ((const float4*)src)[j];
  ushort4 o;
  o.x = f2bf(f.x); o.y = f2bf(f.y); o.z = f2bf(f.z); o.w = f2bf(f.w);
  ((ushort4*)dst)[j] = o;
}

// ---------- GEMM: C[M][N] = A[M][K] * Bt[N][K]^T (+bias) ----------
// (256,3): 3 blocks/CU residency (unified reg use ~136 <= 170)
__global__ __launch_bounds__(256, 3) void gemm_bt(
    const unsigned short* __restrict__ A,
    const unsigned short* __restrict__ Bt,
    const float* __restrict__ bias,
    float* __restrict__ C, int M, int N, int K) {
  __shared__ unsigned short lds_a[128 * 32];
  __shared__ unsigned short lds_b[128 * 32];
  const int tid = threadIdx.x;
  const int wave = tid >> 6, lane = tid & 63;
  const int quad = lane >> 4, l16 = lane & 15;
  const int row0 = blockIdx.x * 128, col0 = blockIdx.y * 128;
  const int wm = (wave >> 1) * 64, wn = (wave & 1) * 64;

  f32x4 acc[4][4] = {};

  const int e0 = wave * 1024 + lane * 8;
  const int e1 = e0 + 512;
  const unsigned short* Ab0 = A + (size_t)(row0 + (e0 >> 5)) * K + (e0 & 31);
  const unsigned short* Ab1 = A + (size_t)(row0 + (e1 >> 5)) * K + (e1 & 31);
  const unsigned short* Bb0 = Bt + (size_t)(col0 + (e0 >> 5)) * K + (e0 & 31);
  const unsigned short* Bb1 = Bt + (size_t)(col0 + (e1 >> 5)) * K + (e1 & 31);
  unsigned short* la0 = lds_a + wave * 1024;
  unsigned short* la1 = la0 + 512;
  unsigned short* lb0 = lds_b + wave * 1024;
  unsigned short* lb1 = lb0 + 512;

  for (int k0 = 0; k0 < K; k0 += 32) {
    __syncthreads();
    async16(Ab0 + k0, la0);
    async16(Ab1 + k0, la1);
    async16(Bb0 + k0, lb0);
    async16(Bb1 + k0, lb1);
    __syncthreads();
    bf16x8 af[4], bfr[4];
#pragma unroll
    for (int mt = 0; mt < 4; mt++)
      af[mt] = lds_frag(lds_a + (wm + mt * 16 + l16) * 32 + quad * 8);
#pragma unroll
    for (int nt = 0; nt < 4; nt++)
      bfr[nt] = lds_frag(lds_b + (wn + nt * 16 + l16) * 32 + quad * 8);
#pragma unroll
    for (int mt = 0; mt < 4; mt++)
#pragma unroll
      for (int nt = 0; nt < 4; nt++)
        acc[mt][nt] = __builtin_amdgcn_mfma_f32_16x16x32_bf16(
            af[mt], bfr[nt], acc[mt][nt], 0, 0, 0);
  }

#pragma unroll
  for (int mt = 0; mt < 4; mt++) {
#pragma unroll
    for (int nt = 0; nt < 4; nt++) {
      const int c = col0 + wn + nt * 16 + l16;
      const float bv = bias ? bias[c] : 0.0f;
      const int rbase = row0 + wm + mt * 16 + quad * 4;
#pragma unroll
      for (int r = 0; r < 4; r++)
        C[(size_t)(rbase + r) * N + c] = acc[mt][nt][r] + bv;
    }
  }
}

// ---------- split-K GEMM, no atomics: z=0 -> C0, z=1 -> C1 ----------
__global__ __launch_bounds__(256, 3) void gemm_bt_splitk(
    const unsigned short* __restrict__ A,
    const unsigned short* __restrict__ Bt,
    float* __restrict__ C0, float* __restrict__ C1,
    int M, int N, int K, int kslice) {
  __shared__ unsigned short lds_a[128 * 32];
  __shared__ unsigned short lds_b[128 * 32];
  const int tid = threadIdx.x;
  const int wave = tid >> 6, lane = tid & 63;
  const int quad = lane >> 4, l16 = lane & 15;
  const int row0 = blockIdx.x * 128, col0 = blockIdx.y * 128;
  const int kofs = blockIdx.z * kslice;
  float* __restrict__ C = blockIdx.z ? C1 : C0;
  const int wm = (wave >> 1) * 64, wn = (wave & 1) * 64;

  f32x4 acc[4][4] = {};

  const int e0 = wave * 1024 + lane * 8;
  const int e1 = e0 + 512;
  const unsigned short* Ab0 = A + (size_t)(row0 + (e0 >> 5)) * K + kofs + (e0 & 31);
  const unsigned short* Ab1 = A + (size_t)(row0 + (e1 >> 5)) * K + kofs + (e1 & 31);
  const unsigned short* Bb0 = Bt + (size_t)(col0 + (e0 >> 5)) * K + kofs + (e0 & 31);
  const unsigned short* Bb1 = Bt + (size_t)(col0 + (e1 >> 5)) * K + kofs + (e1 & 31);
  unsigned short* la0 = lds_a + wave * 1024;
  unsigned short* la1 = la0 + 512;
  unsigned short* lb0 = lds_b + wave * 1024;
  unsigned short* lb1 = lb0 + 512;

  for (int k0 = 0; k0 < kslice; k0 += 32) {
    __syncthreads();
    async16(Ab0 + k0, la0);
    async16(Ab1 + k0, la1);
    async16(Bb0 + k0, lb0);
    async16(Bb1 + k0, lb1);
    __syncthreads();
    bf16x8 af[4], bfr[4];
#pragma unroll
    for (int mt = 0; mt < 4; mt++)
      af[mt] = lds_frag(lds_a + (wm + mt * 16 + l16) * 32 + quad * 8);
#pragma unroll
    for (int nt = 0; nt < 4; nt++)
      bfr[nt] = lds_frag(lds_b + (wn + nt * 16 + l16) * 32 + quad * 8);
#pragma unroll
    for (int mt = 0; mt < 4; mt++)
#pragma unroll
      for (int nt = 0; nt < 4; nt++)
        acc[mt][nt] = __builtin_amdgcn_mfma_f32_16x16x32_bf16(
            af[mt], bfr[nt], acc[mt][nt], 0, 0, 0);
  }

#pragma unroll
  for (int mt = 0; mt < 4; mt++) {
#pragma unroll
    for (int nt = 0; nt < 4; nt++) {
      const int c = col0 + wn + nt * 16 + l16;
      const int rbase = row0 + wm + mt * 16 + quad * 4;
#pragma unroll
      for (int r = 0; r < 4; r++)
        C[(size_t)(rbase + r) * N + c] = acc[mt][nt][r];
    }
  }
}

// ---------- out += partial (float4) ----------
__global__ void reduce_add(float* __restrict__ out,
                           const float* __restrict__ part, int n4) {
  int i = blockIdx.x * 256 + threadIdx.x;
  if (i >= n4) return;
  float4 a = ((const float4*)out)[i];
  float4 b = ((const float4*)part)[i];
  a.x += b.x; a.y += b.y; a.z += b.z; a.w += b.w;
  ((float4*)out)[i] = a;
}

// ---------- RMSNorm + RoPE, wave-per-head ----------
__global__ __launch_bounds__(256) void norm_rope(
    const float* __restrict__ qkv,
    const float* __restrict__ qw,
    const float* __restrict__ kw,
    unsigned short* __restrict__ q,
    unsigned short* __restrict__ k) {
  const int t = blockIdx.x;
  const int wave = threadIdx.x >> 6, lane = threadIdx.x & 63;
#pragma unroll
  for (int it = 0; it < 10; it++) {
    const int slot = it * 4 + wave;
    const bool isq = slot < 32;
    const float* src = qkv + (size_t)t * QKV_N +
                       (isq ? slot * HD : QSIZE + (slot - 32) * HD);
    const float x0 = src[lane];
    const float x1 = src[lane + 64];
    float ss = x0 * x0 + x1 * x1;
#pragma unroll
    for (int m = 32; m >= 1; m >>= 1) ss += __shfl_xor(ss, m, 64);
    const float rn = rsqrtf(ss * (1.0f / 128.0f) + 1e-5f);
    const float* w = isq ? qw : kw;
    const float y0 = x0 * rn * w[lane];
    const float y1 = x1 * rn * w[lane + 64];
    const float p = __shfl_xor(y0, 32, 64);
    const int j = lane & 31;
    const float inv = exp2f(-(float)j * (13.28771237954945f / 32.0f));
    float s, c;
    sincosf((float)t * inv, &s, &c);
    const float r0 = (lane < 32) ? (y0 * c - p * s) : (y0 * c + p * s);
    unsigned short* dst = isq ? q + ((size_t)slot * T_SEQ + t) * HD
                              : k + ((size_t)(slot - 32) * T_SEQ + t) * HD;
    dst[lane] = f2bf(r0);
    dst[lane + 64] = f2bf(y1);
  }
}

// ---------- V transpose: qkv_f32 v-slice -> Vt[kvh][d][T] bf16 ----------
__global__ __launch_bounds__(256) void transpose_v(
    const float* __restrict__ qkv, unsigned short* __restrict__ vt) {
  __shared__ unsigned short tile[64 * 136];
  const int kvh = blockIdx.x, tt = blockIdx.y;
  const int tid = threadIdx.x;
  {
    const int t_r = tid >> 2, d0 = (tid & 3) * 32;
    const float* src = qkv + (size_t)(tt * 64 + t_r) * QKV_N +
                       (QSIZE + KVSIZE) + kvh * HD + d0;
#pragma unroll
    for (int i = 0; i < 8; i++) {
      float4 f = ((const float4*)src)[i];
      unsigned short* dptr = tile + t_r * 136 + d0 + i * 4;
      dptr[0] = f2bf(f.x); dptr[1] = f2bf(f.y);
      dptr[2] = f2bf(f.z); dptr[3] = f2bf(f.w);
    }
  }
  __syncthreads();
  {
    const int d_r = tid >> 1, t0 = (tid & 1) * 32;
    unsigned short buf[32];
#pragma unroll
    for (int i = 0; i < 32; i++) buf[i] = tile[(t0 + i) * 136 + d_r];
    uint4* dst = (uint4*)(vt + ((size_t)kvh * HD + d_r) * T_SEQ + tt * 64 + t0);
#pragma unroll
    for (int i = 0; i < 4; i++) dst[i] = ((uint4*)buf)[i];
  }
}

// ---------- flash attention (causal, GQA 4:1) ----------
// BC=32, double-buffered K/V staging, one barrier per tile, 3 blocks/CU.
// Prefetch for tile kt+1 issued right after the barrier; its vmcnt(0) drain
// happens at the NEXT barrier, i.e. after a full tile of compute.
#define BC 32
#define KCH 528  /* K chunk: 4 rows x 128 elems + 16 pad */
#define VCH 528  /* V chunk: 16 d-rows x 32 keys + 16 pad */
#define PST 40   /* P row stride (32 keys + 8 pad) */
__global__ __launch_bounds__(256, 3) void attn_fwd(
    const unsigned short* __restrict__ Q,   // [32][2048][128]
    const unsigned short* __restrict__ K,   // [8][2048][128]
    const unsigned short* __restrict__ Vt,  // [8][128][2048]
    unsigned short* __restrict__ O) {       // [2048][4096]
  __shared__ unsigned short lds_k[2][8 * KCH];   // 2 x 8448 B
  __shared__ unsigned short lds_v[2][8 * VCH];   // 2 x 8448 B
  __shared__ unsigned short lds_p[4 * 32 * PST]; // 10240 B  (total 44032 B)

  const int bx = blockIdx.x;
  const int qb = 15 - (bx >> 5);  // LPT: largest-work blocks first
  const int h = bx & 31;
  const int kvh = h >> 2;
  const int tid = threadIdx.x, wave = tid >> 6, lane = tid & 63;
  const int quad = lane >> 4, l16 = lane & 15;
  const int q0 = qb * 128;
  const int mrow0 = q0 + wave * 32;

  bf16x8 qf[2][4];
#pragma unroll
  for (int m = 0; m < 2; m++) {
    const unsigned short* qp =
        Q + ((size_t)h * T_SEQ + mrow0 + m * 16 + l16) * HD + quad * 8;
#pragma unroll
    for (int c2 = 0; c2 < 4; c2++) qf[m][c2] = *(const bf16x8*)(qp + c2 * 32);
  }

  f32x4 o_acc[2][8] = {};
  float lrow[2][4] = {};
  const float l2e_s = 1.4426950408889634f * 0.08838834764831845f;
  const float FMAX = 129.0f;
  const unsigned short* kb = K + (size_t)kvh * T_SEQ * HD;
  const unsigned short* vtb = Vt + (size_t)kvh * HD * T_SEQ;
  unsigned short* pbase = lds_p + wave * 32 * PST;

  // staging coords: K chunk = 4 rows x 128 d; V chunk = 16 d-rows x 32 keys
  const int krr = lane >> 4, krd = (lane & 15) * 8;  // K: row-in-chunk, d
  const int vrr = lane >> 2, vrk = (lane & 3) * 8;   // V: d-row-in-chunk, key

  const int nkt = 4 * (qb + 1);

  // prologue: stage tile 0 into buffer 0 (wave w: chunks w and w+4)
#pragma unroll
  for (int cc = 0; cc < 2; cc++) {
    const int c = wave + cc * 4;
    async16(kb + (size_t)(c * 4 + krr) * HD + krd, lds_k[0] + c * KCH + lane * 8);
    async16(vtb + (size_t)(c * 16 + vrr) * T_SEQ + vrk, lds_v[0] + c * VCH + lane * 8);
  }

  for (int kt = 0; kt < nkt; kt++) {
    const int cur = kt & 1;
    const int kbase = kt * BC;
    __syncthreads();  // drains this wave's prefetch; all waves past kt-1 reads
    if (kt + 1 < nkt) {
      const int nb = kbase + BC;
#pragma unroll
      for (int cc = 0; cc < 2; cc++) {
        const int c = wave + cc * 4;
        async16(kb + (size_t)(nb + c * 4 + krr) * HD + krd,
                lds_k[cur ^ 1] + c * KCH + lane * 8);
        async16(vtb + (size_t)(c * 16 + vrr) * T_SEQ + nb + vrk,
                lds_v[cur ^ 1] + c * VCH + lane * 8);
      }
    }

    if (kbase > mrow0 + 31) continue;  // wave fully masked (uniform per wave)

    // ---- S = Q K^T (2 m-frags x 2 n-frags, contract 128) ----
    f32x4 s[2][2] = {};
#pragma unroll
    for (int c2 = 0; c2 < 4; c2++) {
#pragma unroll
      for (int nt = 0; nt < 2; nt++) {
        bf16x8 kf = lds_frag(lds_k[cur] + (nt * 4 + (l16 >> 2)) * KCH +
                             (l16 & 3) * 128 + c2 * 32 + quad * 8);
        s[0][nt] = __builtin_amdgcn_mfma_f32_16x16x32_bf16(qf[0][c2], kf, s[0][nt], 0, 0, 0);
        s[1][nt] = __builtin_amdgcn_mfma_f32_16x16x32_bf16(qf[1][c2], kf, s[1][nt], 0, 0, 0);
      }
    }

    // ---- softmax weights vs fixed max (exact; no rescale) ----
    const bool domask = (kbase + 31 > mrow0);
#pragma unroll
    for (int m = 0; m < 2; m++) {
#pragma unroll
      for (int r = 0; r < 4; r++) {
        const int row = mrow0 + m * 16 + quad * 4 + r;
        float ps = 0.f;
        unsigned short* pw = pbase + (m * 16 + quad * 4 + r) * PST + l16;
#pragma unroll
        for (int nt = 0; nt < 2; nt++) {
          float x = s[m][nt][r];
          if (domask && (kbase + nt * 16 + l16 > row)) x = -INFINITY;
          const float p = exp2f((x - FMAX) * l2e_s);
          ps += p;
          pw[nt * 16] = f2bf(p);
        }
        lrow[m][r] += ps;
      }
    }
    // P per-wave: in-wave DS ordering, no barrier

    // ---- O += P V (32 keys, 8 d-frags) ----
    bf16x8 pa0 = lds_frag(pbase + l16 * PST + quad * 8);
    bf16x8 pa1 = lds_frag(pbase + (16 + l16) * PST + quad * 8);
#pragma unroll
    for (int dt = 0; dt < 8; dt++) {
      bf16x8 vf = lds_frag(lds_v[cur] + dt * VCH + l16 * 32 + quad * 8);
      o_acc[0][dt] = __builtin_amdgcn_mfma_f32_16x16x32_bf16(pa0, vf, o_acc[0][dt], 0, 0, 0);
      o_acc[1][dt] = __builtin_amdgcn_mfma_f32_16x16x32_bf16(pa1, vf, o_acc[1][dt], 0, 0, 0);
    }
  }

  // ---- epilogue ----
#pragma unroll
  for (int m = 0; m < 2; m++) {
#pragma unroll
    for (int r = 0; r < 4; r++) {
      float l = lrow[m][r];
#pragma unroll
      for (int msk = 1; msk < 16; msk <<= 1) l += __shfl_xor(l, msk, 16);
      const float inv = 1.0f / l;
      const int row = mrow0 + m * 16 + quad * 4 + r;
#pragma unroll
      for (int dt = 0; dt < 8; dt++)
        O[(size_t)row * QSIZE + h * HD + dt * 16 + l16] =
            f2bf(o_acc[m][dt][r] * inv);
    }
  }
}

// ---------- launch ----------
extern "C" void kernel_launch(void* const* d_in, const int* in_sizes, int n_in,
                              void* d_out, int out_size, void* d_ws, size_t ws_size,
                              hipStream_t stream) {
  const float* hidden = (const float*)d_in[1];
  const float* w_qkv  = (const float*)d_in[2];
  const float* b_qkv  = (const float*)d_in[3];
  const float* q_norm = (const float*)d_in[4];
  const float* k_norm = (const float*)d_in[5];
  const float* w_o    = (const float*)d_in[6];
  float* out = (float*)d_out;

  char* ws = (char*)d_ws;
  unsigned short* hidden_bf = (unsigned short*)(ws + 0);          // 16 MB
  unsigned short* wqkv_bf   = (unsigned short*)(ws + 16777216);   // 48 MB
  unsigned short* wo_bf     = (unsigned short*)(ws + 67108864);   // 32 MB
  float*          qkv_f32   = (float*)(ws + 100663296);           // 48 MB
  unsigned short* q_bf      = (unsigned short*)(ws + 150994944);  // 16 MB
  unsigned short* k_bf      = (unsigned short*)(ws + 167772160);  // 4 MB
  unsigned short* vt_bf     = (unsigned short*)(ws + 171966464);  // 4 MB
  unsigned short* attn_bf   = (unsigned short*)(ws + 176160768);  // 16 MB
  // split-K partial aliases qkv_f32 (dead after norm_rope + transpose_v)
  float*          part_f32  = (float*)(ws + 100663296);           // 32 MB

  cvt_all<<<(N1 + N2 + N3 + 255) / 256, 256, 0, stream>>>(
      hidden, w_qkv, w_o, hidden_bf, wqkv_bf, wo_bf);

  gemm_bt<<<dim3(T_SEQ / 128, QKV_N / 128), 256, 0, stream>>>(
      hidden_bf, wqkv_bf, b_qkv, qkv_f32, T_SEQ, QKV_N, HIDDEN);

  norm_rope<<<dim3(T_SEQ), 256, 0, stream>>>(
      qkv_f32, q_norm, k_norm, q_bf, k_bf);

  transpose_v<<<dim3(8, T_SEQ / 64), 256, 0, stream>>>(qkv_f32, vt_bf);

  attn_fwd<<<dim3(512), 256, 0, stream>>>(q_bf, k_bf, vt_bf, attn_bf);

  gemm_bt_splitk<<<dim3(T_SEQ / 128, HIDDEN / 128, 2), 256, 0, stream>>>(
      attn_bf, wo_bf, out, part_f32, T_SEQ, HIDDEN, QSIZE, QSIZE / 2);

  reduce_add<<<(T_SEQ * HIDDEN / 4 + 255) / 256, 256, 0, stream>>>(
      out, part_f32, T_SEQ * HIDDEN / 4);
}